// Round 1
// baseline (2079.972 us; speedup 1.0000x reference)
//
#include <hip/hip_runtime.h>
#include <math.h>

// ---------------------------------------------------------------------------
// LeNet forward, B=8192, fp32.  Stage sizes:
//  x  [8192,1,28,28] -> conv1+relu+pool -> p1 [8192,16,14,14]
//  p1 -> conv2+relu+pool -> p2 [8192,32,7,7]
//  p2 -> conv3+relu+pool(pad1) -> p3 [8192,64,4,4] (=1024 flat)
//  p3 -> fc1+relu -> h4 [8192,256]
//  h4 -> fc2+log_softmax -> out [8192,10]
// ---------------------------------------------------------------------------

// Kernel 1: conv1 (Cin=1) + bias + relu + 2x2 maxpool.  Block = 1 batch.
__global__ __launch_bounds__(256) void conv1_pool(
    const float* __restrict__ x, const float* __restrict__ w1,
    const float* __restrict__ b1, float* __restrict__ p1) {
  __shared__ float xs[32 * 32];   // 28x28 input, zero-padded by 2 each side
  __shared__ float ws[16 * 25];
  __shared__ float bs[16];
  const int b = blockIdx.x;
  const int t = threadIdx.x;

  for (int i = t; i < 32 * 32; i += 256) xs[i] = 0.f;
  for (int i = t; i < 400; i += 256) ws[i] = w1[i];
  if (t < 16) bs[t] = b1[t];
  __syncthreads();
  const float* xb = x + (size_t)b * 784;
  for (int i = t; i < 784; i += 256) {
    int y = i / 28, c = i % 28;
    xs[(y + 2) * 32 + (c + 2)] = xb[i];
  }
  __syncthreads();

  if (t < 196) {
    const int py = t / 14, px = t % 14;
    // 6x6 padded-input window covering the 2x2 pooled conv outputs
    float win[6][6];
#pragma unroll
    for (int r = 0; r < 6; ++r)
#pragma unroll
      for (int c = 0; c < 6; ++c)
        win[r][c] = xs[(2 * py + r) * 32 + 2 * px + c];

    for (int co = 0; co < 16; ++co) {
      float w[25];
#pragma unroll
      for (int i = 0; i < 25; ++i) w[i] = ws[co * 25 + i];
      float m = -1e30f;
#pragma unroll
      for (int dy = 0; dy < 2; ++dy)
#pragma unroll
        for (int dx = 0; dx < 2; ++dx) {
          float acc = bs[co];
#pragma unroll
          for (int ky = 0; ky < 5; ++ky)
#pragma unroll
            for (int kx = 0; kx < 5; ++kx)
              acc = fmaf(win[dy + ky][dx + kx], w[ky * 5 + kx], acc);
          m = fmaxf(m, acc);
        }
      p1[(size_t)b * 3136 + co * 196 + t] = fmaxf(m, 0.f);
    }
  }
}

// Kernel 2: conv2 (16->32) + bias + relu + pool.  Block = 1 batch, 448 thr.
// Thread = (co = t/14, px = t%14), owns acc[y=0..13].
__global__ __launch_bounds__(448) void conv2_pool(
    const float* __restrict__ p1, const float* __restrict__ w2,
    const float* __restrict__ b2, float* __restrict__ p2) {
  __shared__ float in_s[16 * 18 * 18];   // 5184: 14x14 padded by 2
  __shared__ float out_s[32 * 196];      // 6272: pre-pool conv outputs
  __shared__ float w_s[32 * 25];         // per-ci weight slice
  const int b = blockIdx.x;
  const int t = threadIdx.x;

  for (int i = t; i < 16 * 324; i += 448) in_s[i] = 0.f;
  __syncthreads();
  const float* pb = p1 + (size_t)b * 3136;
  for (int i = t; i < 3136; i += 448) {
    int ci = i / 196, r = i % 196;
    int y = r / 14, xx = r % 14;
    in_s[ci * 324 + (y + 2) * 18 + (xx + 2)] = pb[i];
  }
  // (covered by first sync inside ci loop)

  const int co = t / 14;   // 0..31
  const int px = t % 14;
  const float bias = b2[co];
  float acc[14];
#pragma unroll
  for (int y = 0; y < 14; ++y) acc[y] = bias;

  for (int ci = 0; ci < 16; ++ci) {
    __syncthreads();   // protects w_s reuse (and in_s fill on first iter)
    for (int i = t; i < 800; i += 448)
      w_s[i] = w2[(i / 25) * 400 + ci * 25 + (i % 25)];
    __syncthreads();
    float wr[25];
#pragma unroll
    for (int i = 0; i < 25; ++i) wr[i] = w_s[co * 25 + i];
#pragma unroll
    for (int kx = 0; kx < 5; ++kx) {
      float col[18];
#pragma unroll
      for (int r = 0; r < 18; ++r) col[r] = in_s[ci * 324 + r * 18 + px + kx];
#pragma unroll
      for (int ky = 0; ky < 5; ++ky) {
        const float w = wr[ky * 5 + kx];
#pragma unroll
        for (int y = 0; y < 14; ++y) acc[y] = fmaf(col[y + ky], w, acc[y]);
      }
    }
  }
#pragma unroll
  for (int y = 0; y < 14; ++y) out_s[co * 196 + y * 14 + px] = acc[y];
  __syncthreads();

  for (int i = t; i < 32 * 49; i += 448) {
    int c = i / 49, r = i % 49;
    int oy = r / 7, ox = r % 7;
    const float* o = out_s + c * 196 + (2 * oy) * 14 + 2 * ox;
    float m = fmaxf(fmaxf(o[0], o[1]), fmaxf(o[14], o[15]));
    p2[(size_t)b * 1568 + i] = fmaxf(m, 0.f);
  }
}

// Kernel 3: conv3 (32->64) + bias + relu + pool(pad=1).  Block = 1 batch, 448.
// Thread = (co = t/7, px = t%7), owns acc[y=0..6].
__global__ __launch_bounds__(448) void conv3_pool(
    const float* __restrict__ p2, const float* __restrict__ w3,
    const float* __restrict__ b3, float* __restrict__ p3) {
  __shared__ float in_s[32 * 11 * 11];   // 3872: 7x7 padded by 2
  __shared__ float out_s[64 * 49];       // 3136
  __shared__ float w_s[64 * 25];         // per-ci weight slice
  const int b = blockIdx.x;
  const int t = threadIdx.x;

  for (int i = t; i < 32 * 121; i += 448) in_s[i] = 0.f;
  __syncthreads();
  const float* pb = p2 + (size_t)b * 1568;
  for (int i = t; i < 1568; i += 448) {
    int ci = i / 49, r = i % 49;
    int y = r / 7, xx = r % 7;
    in_s[ci * 121 + (y + 2) * 11 + (xx + 2)] = pb[i];
  }

  const int co = t / 7;   // 0..63
  const int px = t % 7;
  const float bias = b3[co];
  float acc[7];
#pragma unroll
  for (int y = 0; y < 7; ++y) acc[y] = bias;

  for (int ci = 0; ci < 32; ++ci) {
    __syncthreads();
    for (int i = t; i < 1600; i += 448)
      w_s[i] = w3[(i / 25) * 800 + ci * 25 + (i % 25)];
    __syncthreads();
    float wr[25];
#pragma unroll
    for (int i = 0; i < 25; ++i) wr[i] = w_s[co * 25 + i];
#pragma unroll
    for (int kx = 0; kx < 5; ++kx) {
      float col[11];
#pragma unroll
      for (int r = 0; r < 11; ++r) col[r] = in_s[ci * 121 + r * 11 + px + kx];
#pragma unroll
      for (int ky = 0; ky < 5; ++ky) {
        const float w = wr[ky * 5 + kx];
#pragma unroll
        for (int y = 0; y < 7; ++y) acc[y] = fmaf(col[y + ky], w, acc[y]);
      }
    }
  }
#pragma unroll
  for (int y = 0; y < 7; ++y) out_s[co * 49 + y * 7 + px] = acc[y];
  __syncthreads();

  // pool with pad=1: out 4x4; window oy covers rows {max(2oy-1,0) .. 2oy}
  for (int i = t; i < 64 * 16; i += 448) {
    int c = i / 16, r = i % 16;
    int oy = r / 4, ox = r % 4;
    int y0 = (oy == 0) ? 0 : 2 * oy - 1, y1 = 2 * oy;
    int x0 = (ox == 0) ? 0 : 2 * ox - 1, x1 = 2 * ox;
    float m = -1e30f;
    for (int y = y0; y <= y1; ++y)
      for (int xx = x0; xx <= x1; ++xx)
        m = fmaxf(m, out_s[c * 49 + y * 7 + xx]);
    p3[(size_t)b * 1024 + i] = fmaxf(m, 0.f);
  }
}

// fw1 [256,1024] -> fw1T [1024,256]
__global__ __launch_bounds__(256) void transpose_fw1(
    const float* __restrict__ fw1, float* __restrict__ fw1T) {
  int i = blockIdx.x * 256 + threadIdx.x;
  if (i < 256 * 1024) {
    int co = i / 1024, k = i % 1024;
    fw1T[k * 256 + co] = fw1[i];
  }
}

// FC1: [8192,1024] @ fw1T [1024,256] + fb1, relu.  Block = 16 batches x 256 co.
__global__ __launch_bounds__(256) void fc1(
    const float* __restrict__ p3, const float* __restrict__ fw1T,
    const float* __restrict__ fb1, float* __restrict__ h4) {
  __shared__ float a_s[256 * 16];   // [k][i], 16 KB
  const int b0 = blockIdx.x * 16;
  const int t = threadIdx.x;        // = output column co
  float acc[16];
#pragma unroll
  for (int i = 0; i < 16; ++i) acc[i] = 0.f;

  for (int kt = 0; kt < 1024; kt += 256) {
    __syncthreads();
#pragma unroll
    for (int j = 0; j < 16; ++j)
      a_s[t * 16 + j] = p3[(size_t)(b0 + j) * 1024 + kt + t];
    __syncthreads();
#pragma unroll 4
    for (int k = 0; k < 256; ++k) {
      const float w = fw1T[(size_t)(kt + k) * 256 + t];
      const float4* ap = (const float4*)(a_s + k * 16);
      float4 a0 = ap[0], a1 = ap[1], a2 = ap[2], a3 = ap[3];
      acc[0]  = fmaf(a0.x, w, acc[0]);  acc[1]  = fmaf(a0.y, w, acc[1]);
      acc[2]  = fmaf(a0.z, w, acc[2]);  acc[3]  = fmaf(a0.w, w, acc[3]);
      acc[4]  = fmaf(a1.x, w, acc[4]);  acc[5]  = fmaf(a1.y, w, acc[5]);
      acc[6]  = fmaf(a1.z, w, acc[6]);  acc[7]  = fmaf(a1.w, w, acc[7]);
      acc[8]  = fmaf(a2.x, w, acc[8]);  acc[9]  = fmaf(a2.y, w, acc[9]);
      acc[10] = fmaf(a2.z, w, acc[10]); acc[11] = fmaf(a2.w, w, acc[11]);
      acc[12] = fmaf(a3.x, w, acc[12]); acc[13] = fmaf(a3.y, w, acc[13]);
      acc[14] = fmaf(a3.z, w, acc[14]); acc[15] = fmaf(a3.w, w, acc[15]);
    }
  }
  const float bias = fb1[t];
#pragma unroll
  for (int i = 0; i < 16; ++i)
    h4[(size_t)(b0 + i) * 256 + t] = fmaxf(acc[i] + bias, 0.f);
}

// FC2 + log_softmax.  One wave per batch row.
__global__ __launch_bounds__(256) void fc2_lsm(
    const float* __restrict__ h4, const float* __restrict__ fw2,
    const float* __restrict__ fb2, float* __restrict__ out) {
  const int wave = threadIdx.x >> 6;
  const int lane = threadIdx.x & 63;
  const int b = blockIdx.x * 4 + wave;
  const float* h = h4 + (size_t)b * 256;
  float acc[10];
#pragma unroll
  for (int o = 0; o < 10; ++o) acc[o] = 0.f;
#pragma unroll
  for (int j = 0; j < 4; ++j) {
    const float a = h[lane + j * 64];
#pragma unroll
    for (int o = 0; o < 10; ++o)
      acc[o] = fmaf(a, fw2[o * 256 + lane + j * 64], acc[o]);
  }
#pragma unroll
  for (int o = 0; o < 10; ++o)
    for (int s = 32; s > 0; s >>= 1) acc[o] += __shfl_down(acc[o], s, 64);
  if (lane == 0) {
    float v[10], m = -1e30f;
#pragma unroll
    for (int o = 0; o < 10; ++o) { v[o] = acc[o] + fb2[o]; m = fmaxf(m, v[o]); }
    float s = 0.f;
#pragma unroll
    for (int o = 0; o < 10; ++o) s += expf(v[o] - m);
    const float lse = m + logf(s);
#pragma unroll
    for (int o = 0; o < 10; ++o) out[(size_t)b * 10 + o] = v[o] - lse;
  }
}

extern "C" void kernel_launch(void* const* d_in, const int* in_sizes, int n_in,
                              void* d_out, int out_size, void* d_ws, size_t ws_size,
                              hipStream_t stream) {
  const float* x   = (const float*)d_in[0];
  const float* w1  = (const float*)d_in[1];
  const float* b1  = (const float*)d_in[2];
  const float* w2  = (const float*)d_in[3];
  const float* b2  = (const float*)d_in[4];
  const float* w3  = (const float*)d_in[5];
  const float* b3  = (const float*)d_in[6];
  const float* fw1 = (const float*)d_in[7];
  const float* fb1 = (const float*)d_in[8];
  const float* fw2 = (const float*)d_in[9];
  const float* fb2 = (const float*)d_in[10];
  float* out = (float*)d_out;

  // Workspace layout (floats), with aliasing (p3/h4 reuse p1's region):
  //   [0 .. 25.69M)   p1   (later: p3 at 0, h4 at 8.39M)
  //   [25.69M .. )    p2   12.85M
  //   [38.54M .. )    fw1T 0.26M
  float* ws   = (float*)d_ws;
  float* p1   = ws;
  float* p2   = ws + 25690112;                 // 8192*3136
  float* fw1T = p2 + 12845056;                 // 8192*1568
  float* p3   = ws;                            // aliases dead p1
  float* h4   = ws + 8388608;                  // after p3 (8192*1024)

  conv1_pool<<<dim3(8192), dim3(256), 0, stream>>>(x, w1, b1, p1);
  transpose_fw1<<<dim3(1024), dim3(256), 0, stream>>>(fw1, fw1T);
  conv2_pool<<<dim3(8192), dim3(448), 0, stream>>>(p1, w2, b2, p2);
  conv3_pool<<<dim3(8192), dim3(448), 0, stream>>>(p2, w3, b3, p3);
  fc1<<<dim3(512), dim3(256), 0, stream>>>(p3, fw1T, fb1, h4);
  fc2_lsm<<<dim3(2048), dim3(256), 0, stream>>>(h4, fw2, fb2, out);
}

// Round 2
// 1567.528 us; speedup vs baseline: 1.3269x; 1.3269x over previous
//
#include <hip/hip_runtime.h>
#include <math.h>

// ---------------------------------------------------------------------------
// LeNet forward, B=8192, fp32.
//  x  [8192,1,28,28] -> conv1+relu+pool -> p1 [8192,16,14,14]
//  p1 -> conv2+relu+pool -> p2 [8192,32,7,7]
//  p2 -> conv3+relu+pool(pad1) -> p3 [8192,64,4,4] (=1024 flat)
//  p3 -> fc1+relu -> h4 [8192,256]
//  h4 -> fc2+log_softmax -> out [8192,10]
// ---------------------------------------------------------------------------

// Kernel 1: conv1 (Cin=1) + bias + relu + 2x2 maxpool.  Block = 1 batch.
__global__ __launch_bounds__(256) void conv1_pool(
    const float* __restrict__ x, const float* __restrict__ w1,
    const float* __restrict__ b1, float* __restrict__ p1) {
  __shared__ float xs[32 * 32];   // 28x28 input, zero-padded by 2 each side
  __shared__ float ws[16 * 25];
  __shared__ float bs[16];
  const int b = blockIdx.x;
  const int t = threadIdx.x;

  for (int i = t; i < 32 * 32; i += 256) xs[i] = 0.f;
  for (int i = t; i < 400; i += 256) ws[i] = w1[i];
  if (t < 16) bs[t] = b1[t];
  __syncthreads();
  const float* xb = x + (size_t)b * 784;
  for (int i = t; i < 784; i += 256) {
    int y = i / 28, c = i % 28;
    xs[(y + 2) * 32 + (c + 2)] = xb[i];
  }
  __syncthreads();

  if (t < 196) {
    const int py = t / 14, px = t % 14;
    float win[6][6];
#pragma unroll
    for (int r = 0; r < 6; ++r)
#pragma unroll
      for (int c = 0; c < 6; ++c)
        win[r][c] = xs[(2 * py + r) * 32 + 2 * px + c];

    for (int co = 0; co < 16; ++co) {
      float w[25];
#pragma unroll
      for (int i = 0; i < 25; ++i) w[i] = ws[co * 25 + i];
      float m = -1e30f;
#pragma unroll
      for (int dy = 0; dy < 2; ++dy)
#pragma unroll
        for (int dx = 0; dx < 2; ++dx) {
          float acc = bs[co];
#pragma unroll
          for (int ky = 0; ky < 5; ++ky)
#pragma unroll
            for (int kx = 0; kx < 5; ++kx)
              acc = fmaf(win[dy + ky][dx + kx], w[ky * 5 + kx], acc);
          m = fmaxf(m, acc);
        }
      p1[(size_t)b * 3136 + co * 196 + t] = fmaxf(m, 0.f);
    }
  }
}

// Kernel 2: conv2 (16->32) + bias + relu + pool.
// Block = 448 thr = 2 images x (16 co-pairs x 14 px).  Thread owns
// co in {cp, cp+16}, full y column (acc[2][14]).  Weights direct
// global->reg per ci (no barriers in ci loop).  LDS input is
// column-major [ci][x][y], col stride 20 words (16B aligned, banks spread).
__global__ __launch_bounds__(448) void conv2_pool(
    const float* __restrict__ p1, const float* __restrict__ w2,
    const float* __restrict__ b2, float* __restrict__ p2) {
  __shared__ float smem[12544];   // in: 2*5760=11520; out: 2*6272=12544 (alias)
  const int bb = blockIdx.x;
  const int t = threadIdx.x;
  const int img = t / 224;
  const int r = t % 224;
  const int cp = r / 14;    // 0..15
  const int px = r % 14;

  for (int i = t; i < 11520; i += 448) smem[i] = 0.f;
  __syncthreads();
  for (int i = t; i < 2 * 3136; i += 448) {
    int im = i / 3136, j = i % 3136;
    int ci = j / 196, rr = j % 196;
    int y = rr / 14, xx = rr % 14;
    smem[im * 5760 + ci * 360 + (xx + 2) * 20 + (y + 2)] =
        p1[(size_t)(bb * 2 + im) * 3136 + j];
  }
  __syncthreads();

  float acc0[14], acc1[14];
  const float bias0 = b2[cp], bias1 = b2[cp + 16];
#pragma unroll
  for (int y = 0; y < 14; ++y) { acc0[y] = bias0; acc1[y] = bias1; }

  const int inbase = img * 5760;
  for (int ci = 0; ci < 16; ++ci) {
    float wr0[25], wr1[25];
    const float* wp = w2 + cp * 400 + ci * 25;
#pragma unroll
    for (int i = 0; i < 25; ++i) { wr0[i] = wp[i]; wr1[i] = wp[16 * 400 + i]; }
    const int cb = inbase + ci * 360 + px * 20;
#pragma unroll
    for (int kx = 0; kx < 5; ++kx) {
      float col[18];
#pragma unroll
      for (int rr = 0; rr < 18; ++rr) col[rr] = smem[cb + kx * 20 + rr];
#pragma unroll
      for (int ky = 0; ky < 5; ++ky) {
        const float w0 = wr0[ky * 5 + kx], w1 = wr1[ky * 5 + kx];
#pragma unroll
        for (int y = 0; y < 14; ++y) {
          acc0[y] = fmaf(col[y + ky], w0, acc0[y]);
          acc1[y] = fmaf(col[y + ky], w1, acc1[y]);
        }
      }
    }
  }
  __syncthreads();   // all in-reads done; reuse smem as out buffer
#pragma unroll
  for (int y = 0; y < 14; ++y) {
    smem[img * 6272 + cp * 196 + y * 14 + px] = acc0[y];
    smem[img * 6272 + (cp + 16) * 196 + y * 14 + px] = acc1[y];
  }
  __syncthreads();

  for (int i = t; i < 2 * 1568; i += 448) {
    int im = i / 1568, j = i % 1568;
    int c = j / 49, rr = j % 49;
    int oy = rr / 7, ox = rr % 7;
    const float* o = smem + im * 6272 + c * 196 + (2 * oy) * 14 + 2 * ox;
    float m = fmaxf(fmaxf(o[0], o[1]), fmaxf(o[14], o[15]));
    p2[(size_t)(bb * 2 + im) * 1568 + j] = fmaxf(m, 0.f);
  }
}

// Kernel 3: conv3 (32->64) + bias + relu + pool(pad=1).
// Block = 448 thr = 2 images x (32 co-pairs x 7 px).  Thread owns
// co in {cp, cp+32}, acc[2][7].  Same structure as conv2.
// LDS input column-major [ci][x][y], col stride 12 words.
__global__ __launch_bounds__(448) void conv3_pool(
    const float* __restrict__ p2, const float* __restrict__ w3,
    const float* __restrict__ b3, float* __restrict__ p3) {
  __shared__ float smem[8448];   // in: 2*4224; out: 2*3136 (alias)
  const int bb = blockIdx.x;
  const int t = threadIdx.x;
  const int img = t / 224;
  const int r = t % 224;
  const int cp = r / 7;    // 0..31
  const int px = r % 7;

  for (int i = t; i < 8448; i += 448) smem[i] = 0.f;
  __syncthreads();
  for (int i = t; i < 2 * 1568; i += 448) {
    int im = i / 1568, j = i % 1568;
    int ci = j / 49, rr = j % 49;
    int y = rr / 7, xx = rr % 7;
    smem[im * 4224 + ci * 132 + (xx + 2) * 12 + (y + 2)] =
        p2[(size_t)(bb * 2 + im) * 1568 + j];
  }
  __syncthreads();

  float acc0[7], acc1[7];
  const float bias0 = b3[cp], bias1 = b3[cp + 32];
#pragma unroll
  for (int y = 0; y < 7; ++y) { acc0[y] = bias0; acc1[y] = bias1; }

  const int inbase = img * 4224;
  for (int ci = 0; ci < 32; ++ci) {
    float wr0[25], wr1[25];
    const float* wp = w3 + cp * 800 + ci * 25;
#pragma unroll
    for (int i = 0; i < 25; ++i) { wr0[i] = wp[i]; wr1[i] = wp[32 * 800 + i]; }
    const int cb = inbase + ci * 132 + px * 12;
#pragma unroll
    for (int kx = 0; kx < 5; ++kx) {
      float col[11];
#pragma unroll
      for (int rr = 0; rr < 11; ++rr) col[rr] = smem[cb + kx * 12 + rr];
#pragma unroll
      for (int ky = 0; ky < 5; ++ky) {
        const float w0 = wr0[ky * 5 + kx], w1 = wr1[ky * 5 + kx];
#pragma unroll
        for (int y = 0; y < 7; ++y) {
          acc0[y] = fmaf(col[y + ky], w0, acc0[y]);
          acc1[y] = fmaf(col[y + ky], w1, acc1[y]);
        }
      }
    }
  }
  __syncthreads();   // reuse smem as out buffer
#pragma unroll
  for (int y = 0; y < 7; ++y) {
    smem[img * 3136 + cp * 49 + y * 7 + px] = acc0[y];
    smem[img * 3136 + (cp + 32) * 49 + y * 7 + px] = acc1[y];
  }
  __syncthreads();

  for (int i = t; i < 2 * 1024; i += 448) {
    int im = i / 1024, j = i % 1024;
    int c = j / 16, rr = j % 16;
    int oy = rr / 4, ox = rr % 4;
    int y0 = (oy == 0) ? 0 : 2 * oy - 1, y1 = 2 * oy;
    int x0 = (ox == 0) ? 0 : 2 * ox - 1, x1 = 2 * ox;
    float m = -1e30f;
    for (int y = y0; y <= y1; ++y)
      for (int xx = x0; xx <= x1; ++xx)
        m = fmaxf(m, smem[im * 3136 + c * 49 + y * 7 + xx]);
    p3[(size_t)(bb * 2 + im) * 1024 + j] = fmaxf(m, 0.f);
  }
}

// fw1 [256,1024] -> fw1T [1024,256]
__global__ __launch_bounds__(256) void transpose_fw1(
    const float* __restrict__ fw1, float* __restrict__ fw1T) {
  int i = blockIdx.x * 256 + threadIdx.x;
  if (i < 256 * 1024) {
    int co = i / 1024, k = i % 1024;
    fw1T[k * 256 + co] = fw1[i];
  }
}

// FC1: [8192,1024] @ fw1T [1024,256] + fb1, relu.  Block = 16 batches x 256 co.
__global__ __launch_bounds__(256) void fc1(
    const float* __restrict__ p3, const float* __restrict__ fw1T,
    const float* __restrict__ fb1, float* __restrict__ h4) {
  __shared__ float a_s[256 * 16];   // [k][i], 16 KB
  const int b0 = blockIdx.x * 16;
  const int t = threadIdx.x;        // = output column co
  float acc[16];
#pragma unroll
  for (int i = 0; i < 16; ++i) acc[i] = 0.f;

  for (int kt = 0; kt < 1024; kt += 256) {
    __syncthreads();
#pragma unroll
    for (int j = 0; j < 16; ++j)
      a_s[t * 16 + j] = p3[(size_t)(b0 + j) * 1024 + kt + t];
    __syncthreads();
#pragma unroll 4
    for (int k = 0; k < 256; ++k) {
      const float w = fw1T[(size_t)(kt + k) * 256 + t];
      const float4* ap = (const float4*)(a_s + k * 16);
      float4 a0 = ap[0], a1 = ap[1], a2 = ap[2], a3 = ap[3];
      acc[0]  = fmaf(a0.x, w, acc[0]);  acc[1]  = fmaf(a0.y, w, acc[1]);
      acc[2]  = fmaf(a0.z, w, acc[2]);  acc[3]  = fmaf(a0.w, w, acc[3]);
      acc[4]  = fmaf(a1.x, w, acc[4]);  acc[5]  = fmaf(a1.y, w, acc[5]);
      acc[6]  = fmaf(a1.z, w, acc[6]);  acc[7]  = fmaf(a1.w, w, acc[7]);
      acc[8]  = fmaf(a2.x, w, acc[8]);  acc[9]  = fmaf(a2.y, w, acc[9]);
      acc[10] = fmaf(a2.z, w, acc[10]); acc[11] = fmaf(a2.w, w, acc[11]);
      acc[12] = fmaf(a3.x, w, acc[12]); acc[13] = fmaf(a3.y, w, acc[13]);
      acc[14] = fmaf(a3.z, w, acc[14]); acc[15] = fmaf(a3.w, w, acc[15]);
    }
  }
  const float bias = fb1[t];
#pragma unroll
  for (int i = 0; i < 16; ++i)
    h4[(size_t)(b0 + i) * 256 + t] = fmaxf(acc[i] + bias, 0.f);
}

// FC2 + log_softmax.  One wave per batch row.
__global__ __launch_bounds__(256) void fc2_lsm(
    const float* __restrict__ h4, const float* __restrict__ fw2,
    const float* __restrict__ fb2, float* __restrict__ out) {
  const int wave = threadIdx.x >> 6;
  const int lane = threadIdx.x & 63;
  const int b = blockIdx.x * 4 + wave;
  const float* h = h4 + (size_t)b * 256;
  float acc[10];
#pragma unroll
  for (int o = 0; o < 10; ++o) acc[o] = 0.f;
#pragma unroll
  for (int j = 0; j < 4; ++j) {
    const float a = h[lane + j * 64];
#pragma unroll
    for (int o = 0; o < 10; ++o)
      acc[o] = fmaf(a, fw2[o * 256 + lane + j * 64], acc[o]);
  }
#pragma unroll
  for (int o = 0; o < 10; ++o)
    for (int s = 32; s > 0; s >>= 1) acc[o] += __shfl_down(acc[o], s, 64);
  if (lane == 0) {
    float v[10], m = -1e30f;
#pragma unroll
    for (int o = 0; o < 10; ++o) { v[o] = acc[o] + fb2[o]; m = fmaxf(m, v[o]); }
    float s = 0.f;
#pragma unroll
    for (int o = 0; o < 10; ++o) s += expf(v[o] - m);
    const float lse = m + logf(s);
#pragma unroll
    for (int o = 0; o < 10; ++o) out[(size_t)b * 10 + o] = v[o] - lse;
  }
}

extern "C" void kernel_launch(void* const* d_in, const int* in_sizes, int n_in,
                              void* d_out, int out_size, void* d_ws, size_t ws_size,
                              hipStream_t stream) {
  const float* x   = (const float*)d_in[0];
  const float* w1  = (const float*)d_in[1];
  const float* b1  = (const float*)d_in[2];
  const float* w2  = (const float*)d_in[3];
  const float* b2  = (const float*)d_in[4];
  const float* w3  = (const float*)d_in[5];
  const float* b3  = (const float*)d_in[6];
  const float* fw1 = (const float*)d_in[7];
  const float* fb1 = (const float*)d_in[8];
  const float* fw2 = (const float*)d_in[9];
  const float* fb2 = (const float*)d_in[10];
  float* out = (float*)d_out;

  float* ws   = (float*)d_ws;
  float* p1   = ws;
  float* p2   = ws + 25690112;                 // 8192*3136
  float* fw1T = p2 + 12845056;                 // 8192*1568
  float* p3   = ws;                            // aliases dead p1
  float* h4   = ws + 8388608;                  // after p3 (8192*1024)

  conv1_pool<<<dim3(8192), dim3(256), 0, stream>>>(x, w1, b1, p1);
  transpose_fw1<<<dim3(1024), dim3(256), 0, stream>>>(fw1, fw1T);
  conv2_pool<<<dim3(4096), dim3(448), 0, stream>>>(p1, w2, b2, p2);
  conv3_pool<<<dim3(4096), dim3(448), 0, stream>>>(p2, w3, b3, p3);
  fc1<<<dim3(512), dim3(256), 0, stream>>>(p3, fw1T, fb1, h4);
  fc2_lsm<<<dim3(2048), dim3(256), 0, stream>>>(h4, fw2, fb2, out);
}

// Round 3
// 316.389 us; speedup vs baseline: 6.5741x; 4.9544x over previous
//
#include <hip/hip_runtime.h>
#include <hip/hip_bf16.h>
#include <math.h>

// ---------------------------------------------------------------------------
// LeNet forward, B=8192.  bf16 MFMA for conv2/conv3/fc1; fp32 for conv1/fc2.
//  x[8192,1,28,28] -conv1+pool-> p1 bf16 [img][196pix][16ci]   (channel-last)
//  p1 -conv2+pool->  p2 bf16 [img][49pix][32ci]                (channel-last)
//  p2 -conv3+pool->  p3 bf16 [img][1024] (k = co*16 + pix, ref flatten order)
//  p3 -fc1->         h4 f32  [8192][256]
//  h4 -fc2+lsm->     out f32 [8192][10]
// ---------------------------------------------------------------------------

typedef short bf16x8 __attribute__((ext_vector_type(8)));
typedef float f32x4 __attribute__((ext_vector_type(4)));
typedef unsigned short u16;
#define MFMA16 __builtin_amdgcn_mfma_f32_16x16x32_bf16

__device__ __forceinline__ u16 f2b(float f) {
  __hip_bfloat16 h = __float2bfloat16(f);
  return *reinterpret_cast<u16*>(&h);
}

// ---------------- weight pre-pack kernels (lane-major fragments) ----------
// Bp2: [c13][nt2][lane64][j8]; k = tap*16+ci; tap=2c+(lane>>5), ci=((lane>>4)&1)*8+j
__global__ __launch_bounds__(256) void pack_w2(const float* __restrict__ w2,
                                               u16* __restrict__ Bp2) {
  int i = blockIdx.x * 256 + threadIdx.x;           // 13312 total
  int j = i & 7, lane = (i >> 3) & 63, nt = (i >> 9) & 1, c = i >> 10;
  int tap = 2 * c + (lane >> 5);
  int ci = ((lane >> 4) & 1) * 8 + j;
  int co = nt * 16 + (lane & 15);
  float v = (tap < 25) ? w2[co * 400 + ci * 25 + tap] : 0.f;
  Bp2[i] = f2b(v);
}

// Bp3: [c25][nt4][lane64][j8]; k = tap*32+ci; tap=c, ci=(lane>>4)*8+j
__global__ __launch_bounds__(256) void pack_w3(const float* __restrict__ w3,
                                               u16* __restrict__ Bp3) {
  int i = blockIdx.x * 256 + threadIdx.x;           // 51200 total
  int j = i & 7, lane = (i >> 3) & 63, nt = (i >> 9) & 3, c = i >> 11;
  int ci = (lane >> 4) * 8 + j;
  int co = nt * 16 + (lane & 15);
  Bp3[i] = f2b(w3[co * 800 + ci * 25 + c]);
}

// Bp1: [c32][nt16][lane64][j8]; k = c*32 + (lane>>4)*8 + j
__global__ __launch_bounds__(256) void pack_fw1(const float* __restrict__ fw1,
                                                u16* __restrict__ Bp1) {
  int i = blockIdx.x * 256 + threadIdx.x;           // 262144 total
  int j = i & 7, lane = (i >> 3) & 63, nt = (i >> 9) & 15, c = i >> 13;
  int k = c * 32 + (lane >> 4) * 8 + j;
  int col = nt * 16 + (lane & 15);
  Bp1[i] = f2b(fw1[col * 1024 + k]);
}

// ---------------- conv1 (fp32 VALU) + pool -> bf16 channel-last -----------
__global__ __launch_bounds__(256) void conv1_pool(
    const float* __restrict__ x, const float* __restrict__ w1,
    const float* __restrict__ b1, u16* __restrict__ p1) {
  __shared__ float xs[32 * 32];
  __shared__ float ws[16 * 25];
  __shared__ float bs[16];
  const int b = blockIdx.x;
  const int t = threadIdx.x;

  for (int i = t; i < 1024; i += 256) xs[i] = 0.f;
  for (int i = t; i < 400; i += 256) ws[i] = w1[i];
  if (t < 16) bs[t] = b1[t];
  __syncthreads();
  const float* xb = x + (size_t)b * 784;
  for (int i = t; i < 784; i += 256) {
    int y = i / 28, c = i % 28;
    xs[(y + 2) * 32 + (c + 2)] = xb[i];
  }
  __syncthreads();

  if (t < 196) {
    const int py = t / 14, px = t % 14;
    float win[6][6];
#pragma unroll
    for (int r = 0; r < 6; ++r)
#pragma unroll
      for (int c = 0; c < 6; ++c)
        win[r][c] = xs[(2 * py + r) * 32 + 2 * px + c];

    u16 res[16];
#pragma unroll
    for (int co = 0; co < 16; ++co) {
      float w[25];
#pragma unroll
      for (int i = 0; i < 25; ++i) w[i] = ws[co * 25 + i];
      float m = -1e30f;
#pragma unroll
      for (int dy = 0; dy < 2; ++dy)
#pragma unroll
        for (int dx = 0; dx < 2; ++dx) {
          float acc = bs[co];
#pragma unroll
          for (int ky = 0; ky < 5; ++ky)
#pragma unroll
            for (int kx = 0; kx < 5; ++kx)
              acc = fmaf(win[dy + ky][dx + kx], w[ky * 5 + kx], acc);
          m = fmaxf(m, acc);
        }
      res[co] = f2b(fmaxf(m, 0.f));
    }
    u16* dst = p1 + (((size_t)b * 196 + t) << 4);
    *(int4*)dst = *(int4*)res;
    *(int4*)(dst + 8) = *(int4*)(res + 8);
  }
}

// ---------------- conv2 MFMA: 2 img/block, M=392, N=32, K=400(13 chunks) ---
__global__ __launch_bounds__(256) void conv2_mfma(
    const u16* __restrict__ p1, const u16* __restrict__ Bp2,
    const float* __restrict__ b2, u16* __restrict__ p2) {
  __shared__ u16 smem[15552];   // in: 2 x [18][18][24ci-pad] ; out aliases
  const int bb = blockIdx.x;
  const int t = threadIdx.x;
  const int w = t >> 6, l = t & 63;

  for (int i = t; i < 15552; i += 256) smem[i] = 0;
  __syncthreads();
  for (int i = t; i < 784; i += 256) {   // 2img x 14y x 14x x 2 half-rows
    int half = i & 1, xx = (i >> 1) % 14, y = ((i >> 1) / 14) % 14, img = i / 392;
    const int4 v = *(const int4*)(p1 + (((size_t)(bb * 2 + img) * 196 + y * 14 + xx) << 4) + half * 8);
    *(int4*)(smem + img * 7776 + ((y + 2) * 18 + (xx + 2)) * 24 + half * 8) = v;
  }
  __syncthreads();

  const int g = l >> 4;
  const int cil = (g & 1) * 8;
  const int tapadd = g >> 1;
  const int nmt = (w == 0) ? 7 : 6;   // M-tiles: w, w+4, ... < 25

  int abase[7];
#pragma unroll
  for (int jj = 0; jj < 7; ++jj) {
    int mt = w + jj * 4;
    int m = mt * 16 + (l & 15); if (m > 391) m = 391;
    int img = m / 196, pix = m % 196;
    int py = pix / 14, px = pix % 14;
    abase[jj] = img * 7776 + (py * 18 + px) * 24 + cil;
  }
  const float bias0 = b2[l & 15], bias1 = b2[16 + (l & 15)];
  f32x4 acc[7][2];
#pragma unroll
  for (int jj = 0; jj < 7; ++jj) {
    acc[jj][0] = (f32x4){bias0, bias0, bias0, bias0};
    acc[jj][1] = (f32x4){bias1, bias1, bias1, bias1};
  }
  const bf16x8* Bb = (const bf16x8*)Bp2;   // idx (c*2+nt)*64 + l
  bf16x8 b0 = Bb[l], b1 = Bb[64 + l];
  for (int c = 0; c < 13; ++c) {
    bf16x8 n0 = b0, n1 = b1;
    if (c < 12) { n0 = Bb[((c + 1) * 2) * 64 + l]; n1 = Bb[((c + 1) * 2 + 1) * 64 + l]; }
    int tp = 2 * c + tapadd; if (tp > 24) tp = 24;   // c=12 upper taps: B is 0
    int ky = tp / 5, kx = tp - ky * 5;
    int off = (ky * 18 + kx) * 24;
#pragma unroll
    for (int jj = 0; jj < 7; ++jj) {
      if (jj < nmt) {
        bf16x8 a = *(const bf16x8*)(smem + abase[jj] + off);
        acc[jj][0] = MFMA16(a, b0, acc[jj][0], 0, 0, 0);
        acc[jj][1] = MFMA16(a, b1, acc[jj][1], 0, 0, 0);
      }
    }
    b0 = n0; b1 = n1;
  }
  __syncthreads();   // all in_s reads done; alias as out buffer
#pragma unroll
  for (int jj = 0; jj < 7; ++jj) {
    if (jj < nmt) {
      int mt = w + jj * 4;
#pragma unroll
      for (int r = 0; r < 4; ++r) {
        int m = mt * 16 + (l >> 4) * 4 + r;
        if (m < 392) {
          int img = m / 196, pix = m % 196;
          smem[img * 6272 + (l & 15) * 196 + pix]        = f2b(fmaxf(acc[jj][0][r], 0.f));
          smem[img * 6272 + (16 + (l & 15)) * 196 + pix] = f2b(fmaxf(acc[jj][1][r], 0.f));
        }
      }
    }
  }
  __syncthreads();
  for (int i = t; i < 3136; i += 256) {   // pool 2x2 -> p2 [img][49][32]
    int co = i & 31, p = (i >> 5) % 49, img = i / 1568;
    int oy = p / 7, ox = p % 7;
    int base = img * 6272 + co * 196 + oy * 28 + ox * 2;
    u16 m0 = smem[base], m1 = smem[base + 1], m2 = smem[base + 14], m3 = smem[base + 15];
    u16 a = m0 > m1 ? m0 : m1, bq = m2 > m3 ? m2 : m3;   // nonneg bf16: uint max ok
    p2[(((size_t)(bb * 2 + img) * 49 + p) << 5) + co] = a > bq ? a : bq;
  }
}

// ---------------- conv3 MFMA: 4 img/block, M=196, N=64, K=800(25 chunks) ---
__global__ __launch_bounds__(256) void conv3_mfma(
    const u16* __restrict__ p2, const u16* __restrict__ Bp3,
    const float* __restrict__ b3, u16* __restrict__ p3) {
  __shared__ u16 smem[19360];   // in: 4 x [11][11][40ci-pad]; out aliases
  const int bb = blockIdx.x;
  const int t = threadIdx.x;
  const int w = t >> 6, l = t & 63;

  for (int i = t; i < 19360; i += 256) smem[i] = 0;
  __syncthreads();
  for (int i = t; i < 784; i += 256) {   // 4img x 7y x 7x x 4 ci-octs
    int oct = i & 3, xx = (i >> 2) % 7, y = ((i >> 2) / 7) % 7, img = i / 196;
    const int4 v = *(const int4*)(p2 + (((size_t)(bb * 4 + img) * 49 + y * 7 + xx) << 5) + oct * 8);
    *(int4*)(smem + img * 4840 + ((y + 2) * 11 + (xx + 2)) * 40 + oct * 8) = v;
  }
  __syncthreads();

  const int g = l >> 4;
  const int cil = g * 8;
  const int nmt = (w == 0) ? 4 : 3;   // M-tiles: w, w+4, ... < 13

  int abase[4];
#pragma unroll
  for (int jj = 0; jj < 4; ++jj) {
    int mt = w + jj * 4;
    int m = mt * 16 + (l & 15); if (m > 195) m = 195;
    int img = m / 49, pix = m % 49;
    int py = pix / 7, px = pix % 7;
    abase[jj] = img * 4840 + (py * 11 + px) * 40 + cil;
  }
  f32x4 acc[4][4];
#pragma unroll
  for (int q = 0; q < 4; ++q) {
    float bias = b3[q * 16 + (l & 15)];
#pragma unroll
    for (int jj = 0; jj < 4; ++jj)
      acc[jj][q] = (f32x4){bias, bias, bias, bias};
  }
  const bf16x8* Bb = (const bf16x8*)Bp3;   // idx (c*4+nt)*64 + l
  bf16x8 bfr[4];
#pragma unroll
  for (int q = 0; q < 4; ++q) bfr[q] = Bb[q * 64 + l];
  for (int c = 0; c < 25; ++c) {
    bf16x8 nb0 = bfr[0], nb1 = bfr[1], nb2 = bfr[2], nb3 = bfr[3];
    if (c < 24) {
      nb0 = Bb[((c + 1) * 4 + 0) * 64 + l];
      nb1 = Bb[((c + 1) * 4 + 1) * 64 + l];
      nb2 = Bb[((c + 1) * 4 + 2) * 64 + l];
      nb3 = Bb[((c + 1) * 4 + 3) * 64 + l];
    }
    int ky = c / 5, kx = c - ky * 5;
    int off = (ky * 11 + kx) * 40;
#pragma unroll
    for (int jj = 0; jj < 4; ++jj) {
      if (jj < nmt) {
        bf16x8 a = *(const bf16x8*)(smem + abase[jj] + off);
        acc[jj][0] = MFMA16(a, bfr[0], acc[jj][0], 0, 0, 0);
        acc[jj][1] = MFMA16(a, bfr[1], acc[jj][1], 0, 0, 0);
        acc[jj][2] = MFMA16(a, bfr[2], acc[jj][2], 0, 0, 0);
        acc[jj][3] = MFMA16(a, bfr[3], acc[jj][3], 0, 0, 0);
      }
    }
    bfr[0] = nb0; bfr[1] = nb1; bfr[2] = nb2; bfr[3] = nb3;
  }
  __syncthreads();   // alias smem as out buffer [img][64co][49]
#pragma unroll
  for (int jj = 0; jj < 4; ++jj) {
    if (jj < nmt) {
      int mt = w + jj * 4;
#pragma unroll
      for (int q = 0; q < 4; ++q)
#pragma unroll
        for (int r = 0; r < 4; ++r) {
          int m = mt * 16 + (l >> 4) * 4 + r;
          if (m < 196) {
            int img = m / 49, pix = m % 49;
            smem[img * 3136 + (q * 16 + (l & 15)) * 49 + pix] = f2b(fmaxf(acc[jj][q][r], 0.f));
          }
        }
    }
  }
  __syncthreads();
  for (int i = t; i < 4096; i += 256) {   // pool pad=1 -> p3 [img][co*16+p]
    int co = i & 63, p = (i >> 6) % 16, img = i >> 10;
    int oy = p >> 2, ox = p & 3;
    int y0 = oy ? 2 * oy - 1 : 0, y1 = 2 * oy;
    int x0 = ox ? 2 * ox - 1 : 0, x1 = 2 * ox;
    u16 mm = 0;   // relu'd values are >= 0
    for (int y = y0; y <= y1; ++y)
      for (int xx = x0; xx <= x1; ++xx) {
        u16 v = smem[img * 3136 + co * 49 + y * 7 + xx];
        if (v > mm) mm = v;
      }
    p3[(((size_t)(bb * 4 + img)) << 10) + co * 16 + p] = mm;
  }
}

// ---------------- fc1 MFMA: M=8192,N=256,K=1024; no LDS, prefetch ---------
__global__ __launch_bounds__(256) void fc1_mfma(
    const u16* __restrict__ p3, const u16* __restrict__ Bp1,
    const float* __restrict__ fb1, float* __restrict__ h4) {
  const int bid = blockIdx.x;
  const int mb = bid >> 1, nb = bid & 1;   // 128 x 2
  const int t = threadIdx.x;
  const int w = t >> 6, l = t & 63;
  const int g = l >> 4;

  const int mt0 = mb * 4 + (w >> 1) * 2;     // 2 M-tiles
  const int ntbase = nb * 8 + (w & 1) * 4;   // 4 N-tiles

  size_t arow0 = (size_t)(mt0 * 16 + (l & 15)) * 1024 + g * 8;
  size_t arow1 = arow0 + 16 * 1024;
  const bf16x8* Bb = (const bf16x8*)Bp1;     // idx (c*16+nt)*64 + l

  f32x4 acc[2][4];
#pragma unroll
  for (int i = 0; i < 2; ++i)
#pragma unroll
    for (int q = 0; q < 4; ++q) acc[i][q] = (f32x4){0.f, 0.f, 0.f, 0.f};

  bf16x8 a0 = *(const bf16x8*)(p3 + arow0);
  bf16x8 a1 = *(const bf16x8*)(p3 + arow1);
  bf16x8 bq0 = Bb[(ntbase + 0) * 64 + l], bq1 = Bb[(ntbase + 1) * 64 + l];
  bf16x8 bq2 = Bb[(ntbase + 2) * 64 + l], bq3 = Bb[(ntbase + 3) * 64 + l];

  for (int c = 0; c < 32; ++c) {
    bf16x8 na0 = a0, na1 = a1, nb0 = bq0, nb1 = bq1, nb2 = bq2, nb3 = bq3;
    if (c < 31) {
      na0 = *(const bf16x8*)(p3 + arow0 + (c + 1) * 32);
      na1 = *(const bf16x8*)(p3 + arow1 + (c + 1) * 32);
      nb0 = Bb[((c + 1) * 16 + ntbase + 0) * 64 + l];
      nb1 = Bb[((c + 1) * 16 + ntbase + 1) * 64 + l];
      nb2 = Bb[((c + 1) * 16 + ntbase + 2) * 64 + l];
      nb3 = Bb[((c + 1) * 16 + ntbase + 3) * 64 + l];
    }
    acc[0][0] = MFMA16(a0, bq0, acc[0][0], 0, 0, 0);
    acc[0][1] = MFMA16(a0, bq1, acc[0][1], 0, 0, 0);
    acc[0][2] = MFMA16(a0, bq2, acc[0][2], 0, 0, 0);
    acc[0][3] = MFMA16(a0, bq3, acc[0][3], 0, 0, 0);
    acc[1][0] = MFMA16(a1, bq0, acc[1][0], 0, 0, 0);
    acc[1][1] = MFMA16(a1, bq1, acc[1][1], 0, 0, 0);
    acc[1][2] = MFMA16(a1, bq2, acc[1][2], 0, 0, 0);
    acc[1][3] = MFMA16(a1, bq3, acc[1][3], 0, 0, 0);
    a0 = na0; a1 = na1; bq0 = nb0; bq1 = nb1; bq2 = nb2; bq3 = nb3;
  }
#pragma unroll
  for (int i = 0; i < 2; ++i) {
    int mrow = (mt0 + i) * 16 + g * 4;
#pragma unroll
    for (int q = 0; q < 4; ++q) {
      int col = (ntbase + q) * 16 + (l & 15);
      float bias = fb1[col];
#pragma unroll
      for (int r = 0; r < 4; ++r)
        h4[(size_t)(mrow + r) * 256 + col] = fmaxf(acc[i][q][r] + bias, 0.f);
    }
  }
}

// ---------------- fc2 + log_softmax (fp32), one wave per row --------------
__global__ __launch_bounds__(256) void fc2_lsm(
    const float* __restrict__ h4, const float* __restrict__ fw2,
    const float* __restrict__ fb2, float* __restrict__ out) {
  const int wave = threadIdx.x >> 6;
  const int lane = threadIdx.x & 63;
  const int b = blockIdx.x * 4 + wave;
  const float* h = h4 + (size_t)b * 256;
  float acc[10];
#pragma unroll
  for (int o = 0; o < 10; ++o) acc[o] = 0.f;
#pragma unroll
  for (int j = 0; j < 4; ++j) {
    const float a = h[lane + j * 64];
#pragma unroll
    for (int o = 0; o < 10; ++o)
      acc[o] = fmaf(a, fw2[o * 256 + lane + j * 64], acc[o]);
  }
#pragma unroll
  for (int o = 0; o < 10; ++o)
    for (int s = 32; s > 0; s >>= 1) acc[o] += __shfl_down(acc[o], s, 64);
  if (lane == 0) {
    float v[10], m = -1e30f;
#pragma unroll
    for (int o = 0; o < 10; ++o) { v[o] = acc[o] + fb2[o]; m = fmaxf(m, v[o]); }
    float s = 0.f;
#pragma unroll
    for (int o = 0; o < 10; ++o) s += expf(v[o] - m);
    const float lse = m + logf(s);
#pragma unroll
    for (int o = 0; o < 10; ++o) out[(size_t)b * 10 + o] = v[o] - lse;
  }
}

extern "C" void kernel_launch(void* const* d_in, const int* in_sizes, int n_in,
                              void* d_out, int out_size, void* d_ws, size_t ws_size,
                              hipStream_t stream) {
  const float* x   = (const float*)d_in[0];
  const float* w1  = (const float*)d_in[1];
  const float* b1  = (const float*)d_in[2];
  const float* w2  = (const float*)d_in[3];
  const float* b2  = (const float*)d_in[4];
  const float* w3  = (const float*)d_in[5];
  const float* b3  = (const float*)d_in[6];
  const float* fw1 = (const float*)d_in[7];
  const float* fb1 = (const float*)d_in[8];
  const float* fw2 = (const float*)d_in[9];
  const float* fb2 = (const float*)d_in[10];
  float* out = (float*)d_out;

  // Workspace byte layout (~103 MB total):
  char* W = (char*)d_ws;
  u16*   p1  = (u16*)(W);                    // 8192*3136*2   = 51,380,224
  u16*   p2  = (u16*)(W + 51380224);         // 8192*1568*2   = 25,690,112
  u16*   p3  = (u16*)(W + 77070336);         // 8192*1024*2   = 16,777,216
  float* h4  = (float*)(W + 93847552);       // 8192*256*4    =  8,388,608
  u16*   Bp2 = (u16*)(W + 102236160);        // 26,624
  u16*   Bp3 = (u16*)(W + 102262784);        // 102,400
  u16*   Bp1 = (u16*)(W + 102365184);        // 524,288

  pack_w2 <<<dim3(52),   dim3(256), 0, stream>>>(w2,  Bp2);
  pack_w3 <<<dim3(200),  dim3(256), 0, stream>>>(w3,  Bp3);
  pack_fw1<<<dim3(1024), dim3(256), 0, stream>>>(fw1, Bp1);
  conv1_pool<<<dim3(8192), dim3(256), 0, stream>>>(x, w1, b1, p1);
  conv2_mfma<<<dim3(4096), dim3(256), 0, stream>>>(p1, Bp2, b2, p2);
  conv3_mfma<<<dim3(2048), dim3(256), 0, stream>>>(p2, Bp3, b3, p3);
  fc1_mfma<<<dim3(256), dim3(256), 0, stream>>>(p3, Bp1, fb1, h4);
  fc2_lsm<<<dim3(2048), dim3(256), 0, stream>>>(h4, fw2, fb2, out);
}